// Round 3
// baseline (625.656 us; speedup 1.0000x reference)
//
#include <hip/hip_runtime.h>
#include <hip/hip_bf16.h>
#include <cmath>

#define N_TOK 32768
#define DIM   256
#define NEXP  8
#define HID   1024
#define BM    64
#define BH    64
#define MAXT  512   // MAXT*BM == N_TOK: covers worst-case expert load

typedef short bf16x8 __attribute__((ext_vector_type(8)));
typedef float f32x4  __attribute__((ext_vector_type(4)));

__device__ __forceinline__ ushort f2bf(float f) {
  unsigned u = __builtin_bit_cast(unsigned, f);
  u += 0x7fffu + ((u >> 16) & 1u);   // RNE; inputs are well-behaved (no NaN/Inf)
  return (ushort)(u >> 16);
}

// lh swizzle: 16B-slot index within a 128B row. Distinct for the C-layout
// store rows {j, j+4, j+8, j+12}; 2-way (free) for read rows R..R+15.
__device__ __forceinline__ int lh_slot(int row) {
  return ((row ^ (row >> 3)) & 7) << 4;
}

// ---------- transpose + cast: src[E][R][C] f32 -> dst[E][C][R] bf16 ----------
__global__ __launch_bounds__(256) void k_transpose_cast(
    const float* __restrict__ src, ushort* __restrict__ dst, int R, int C)
{
  __shared__ float tile[32][33];
  int e = blockIdx.z, rb = blockIdx.y, cb = blockIdx.x;
  int tx = threadIdx.x, ty = threadIdx.y;           // 32 x 8
  const float* s = src + (size_t)e * R * C;
  ushort* d = dst + (size_t)e * R * C;
#pragma unroll
  for (int j = 0; j < 4; ++j)
    tile[ty + 8*j][tx] = s[(size_t)(rb*32 + ty + 8*j) * C + cb*32 + tx];
  __syncthreads();
#pragma unroll
  for (int j = 0; j < 4; ++j)
    d[(size_t)(cb*32 + ty + 8*j) * R + rb*32 + tx] = f2bf(tile[tx][ty + 8*j]);
}

// ---------- router: fp64 logits, softmax, top-2, bucket scatter ----------
__global__ __launch_bounds__(256) void k_router(
    const float* __restrict__ x, const float* __restrict__ grad,
    const float* __restrict__ Wr, const float* __restrict__ br,
    float* __restrict__ probs_out,
    int* __restrict__ cnt, int* __restrict__ tok, float* __restrict__ wgt)
{
  __shared__ float xt[256][33];
  __shared__ float wrs[257*8];
  __shared__ float brs[8];
  __shared__ int lcnt[8], lbase[8];
  int tid = threadIdx.x;
  int n = blockIdx.x * 256 + tid;

  for (int i = tid; i < 257*8; i += 256) wrs[i] = Wr[i];
  if (tid < 8) { brs[tid] = br[tid]; lcnt[tid] = 0; }

  double acc[8] = {0,0,0,0,0,0,0,0};
  for (int ch = 0; ch < 8; ++ch) {
    __syncthreads();
    for (int f = tid; f < 2048; f += 256) {          // 256 rows x 32 cols, float4
      int r = f >> 3, c0 = (f & 7) * 4;
      float4 v = *(const float4*)(x + (size_t)(blockIdx.x*256 + r)*DIM + ch*32 + c0);
      xt[r][c0] = v.x; xt[r][c0+1] = v.y; xt[r][c0+2] = v.z; xt[r][c0+3] = v.w;
    }
    __syncthreads();
#pragma unroll 4
    for (int c = 0; c < 32; ++c) {
      double xv = (double)xt[tid][c];
      const float* wr = &wrs[(ch*32 + c)*8];
#pragma unroll
      for (int e = 0; e < 8; ++e) acc[e] += xv * (double)wr[e];
    }
  }
  double g = (double)grad[n];
  double lg[8];
#pragma unroll
  for (int e = 0; e < 8; ++e) lg[e] = acc[e] + g*(double)wrs[256*8+e] + (double)brs[e];
  double m = lg[0];
#pragma unroll
  for (int e = 1; e < 8; ++e) m = lg[e] > m ? lg[e] : m;
  double p[8], s = 0.0;
#pragma unroll
  for (int e = 0; e < 8; ++e) { p[e] = exp(lg[e]-m); s += p[e]; }
  double inv = 1.0/s;
#pragma unroll
  for (int e = 0; e < 8; ++e) probs_out[(size_t)n*8 + e] = (float)(p[e]*inv);

  // top-2, ties -> lower index (matches lax.top_k)
  int i0 = 0;
#pragma unroll
  for (int e = 1; e < 8; ++e) if (lg[e] > lg[i0]) i0 = e;
  int i1 = (i0 == 0) ? 1 : 0;
#pragma unroll
  for (int e = 0; e < 8; ++e) if (e != i0 && lg[e] > lg[i1]) i1 = e;
  float w0 = (float)(p[i0]*inv), w1 = (float)(p[i1]*inv);

  int p0 = atomicAdd(&lcnt[i0], 1);
  int p1 = atomicAdd(&lcnt[i1], 1);
  __syncthreads();
  if (tid < 8) lbase[tid] = atomicAdd(&cnt[tid], lcnt[tid]);
  __syncthreads();
  tok[i0*N_TOK + lbase[i0] + p0] = n;  wgt[i0*N_TOK + lbase[i0] + p0] = w0;
  tok[i1*N_TOK + lbase[i1] + p1] = n;  wgt[i1*N_TOK + lbase[i1] + p1] = w1;
}

// ---------- fused gathered expert MLP: out += w * (gelu(x@W1+b1)@W2 + b2) ----------
__global__ __launch_bounds__(256, 4) void k_moe(
    const float* __restrict__ x,
    const ushort* __restrict__ w1t,   // [E][H][D] bf16 (transposed)
    const ushort* __restrict__ w2t,   // [E][D][H] bf16 (transposed)
    const float* __restrict__ bias1,  // [E][H]
    const float* __restrict__ bias2,  // [E][D]
    const int* __restrict__ cnt, const int* __restrict__ tok,
    const float* __restrict__ wgt,
    float* __restrict__ out)
{
  // Contiguous per-expert mapping (round-1 behavior): the whole machine works
  // through experts in dispatch order, so each XCD's L2 holds the CURRENT
  // expert's 2 MB of bf16 weights. (The e=bid&7 "XCD affinity" variant
  // thrashed L2: FETCH 67->758 MB.)
  int e    = blockIdx.x / MAXT;
  int tile = blockIdx.x % MAXT;
  int c = cnt[e];
  int row0 = tile * BM;
  if (row0 >= c) return;
  int rows = min(BM, c - row0);

  __shared__ ushort lh[2][BM * BH];   // 16 KB double-buffered h tile

  int tid  = threadIdx.x;
  int lane = tid & 63;
  int wid  = tid >> 6;
  const int l15 = lane & 15;
  const int lk8 = (lane >> 4) * 8;
  const int lr4 = (lane >> 4) * 4;
  const int wr = wid >> 1, wc = wid & 1;   // 2x2 wave grid for GEMM1

  const int*   etok = tok + e * N_TOK + row0;
  const float* ewgt = wgt + e * N_TOK + row0;

  // ---- gather A (x rows) into registers as bf16: areg[fr][k] ----
  bf16x8 areg[2][8];
#pragma unroll
  for (int fr = 0; fr < 2; ++fr) {
    int r = wr*32 + fr*16 + l15;
    int t = etok[min(r, rows - 1)];
    const float* xp = x + (size_t)t * DIM + lk8;
#pragma unroll
    for (int k = 0; k < 8; ++k) {
      float4 u0 = *(const float4*)(xp + k*32);
      float4 u1 = *(const float4*)(xp + k*32 + 4);
      bf16x8 a;
      a[0]=f2bf(u0.x); a[1]=f2bf(u0.y); a[2]=f2bf(u0.z); a[3]=f2bf(u0.w);
      a[4]=f2bf(u1.x); a[5]=f2bf(u1.y); a[6]=f2bf(u1.z); a[7]=f2bf(u1.w);
      areg[fr][k] = a;
    }
  }

  f32x4 accY[4][4];
#pragma unroll
  for (int i = 0; i < 4; ++i)
#pragma unroll
    for (int j = 0; j < 4; ++j) accY[i][j] = (f32x4){0.f,0.f,0.f,0.f};

  const ushort* W1e = w1t + (size_t)e * HID * DIM;
  const ushort* W2e = w2t + (size_t)e * DIM * HID;

  int sl2[4];
#pragma unroll
  for (int fr = 0; fr < 4; ++fr) sl2[fr] = lh_slot(fr*16 + l15);

  for (int chunk = 0; chunk < HID / BH; ++chunk) {
    int h0 = chunk * BH;

    // ---- prefetch this chunk's W2 B-fragments into registers; they are
    // consumed after the barrier, so their latency hides under GEMM1+GELU ----
    bf16x8 bw[2][4];
#pragma unroll
    for (int k2 = 0; k2 < 2; ++k2)
#pragma unroll
      for (int fc = 0; fc < 4; ++fc)
        bw[k2][fc] = *(const bf16x8*)(W2e + (size_t)(wid*64 + fc*16 + l15) * HID
                                      + h0 + k2*32 + lk8);

    f32x4 accH[2][2];
#pragma unroll
    for (int i = 0; i < 2; ++i)
#pragma unroll
      for (int j = 0; j < 2; ++j) accH[i][j] = (f32x4){0.f,0.f,0.f,0.f};

    // GEMM1: h[64x64] = x[64x256] @ W1[256x64], A from registers
#pragma unroll
    for (int k = 0; k < 8; ++k) {
      bf16x8 b0 = *(const bf16x8*)(W1e + (size_t)(h0 + wc*32 +      l15) * DIM + k*32 + lk8);
      bf16x8 b1 = *(const bf16x8*)(W1e + (size_t)(h0 + wc*32 + 16 + l15) * DIM + k*32 + lk8);
      accH[0][0] = __builtin_amdgcn_mfma_f32_16x16x32_bf16(areg[0][k], b0, accH[0][0], 0, 0, 0);
      accH[1][0] = __builtin_amdgcn_mfma_f32_16x16x32_bf16(areg[1][k], b0, accH[1][0], 0, 0, 0);
      accH[0][1] = __builtin_amdgcn_mfma_f32_16x16x32_bf16(areg[0][k], b1, accH[0][1], 0, 0, 0);
      accH[1][1] = __builtin_amdgcn_mfma_f32_16x16x32_bf16(areg[1][k], b1, accH[1][1], 0, 0, 0);
    }

    // exact GELU + bf16 -> swizzled LDS (double buffer)
    ushort* lb = lh[chunk & 1];
#pragma unroll
    for (int fc = 0; fc < 2; ++fc) {
      float bv = bias1[e*HID + h0 + wc*32 + fc*16 + l15];
      int col = wc*32 + fc*16 + l15;
#pragma unroll
      for (int fr = 0; fr < 2; ++fr)
#pragma unroll
        for (int j = 0; j < 4; ++j) {
          int row = wr*32 + fr*16 + lr4 + j;
          float v = accH[fr][fc][j] + bv;
          v = 0.5f * v * (1.0f + erff(v * 0.70710678118654752f));
          *(ushort*)((char*)lb + row*128 + ((col*2) ^ lh_slot(row))) = f2bf(v);
        }
    }
    __syncthreads();

    // GEMM2: y[64x256] += h[64x64] @ W2[64x256], B from prefetched regs
#pragma unroll
    for (int k2 = 0; k2 < 2; ++k2) {
      bf16x8 a2[4];
#pragma unroll
      for (int fr = 0; fr < 4; ++fr) {
        int row = fr*16 + l15;
        a2[fr] = *(const bf16x8*)((const char*)lb + row*128 + (((k2*32 + lk8)*2) ^ sl2[fr]));
      }
#pragma unroll
      for (int fr = 0; fr < 4; ++fr)
#pragma unroll
        for (int fc = 0; fc < 4; ++fc)
          accY[fr][fc] = __builtin_amdgcn_mfma_f32_16x16x32_bf16(a2[fr], bw[k2][fc], accY[fr][fc], 0, 0, 0);
    }
  }

  // epilogue: out[t] += w * (y + b2)
  float b2v[4];
#pragma unroll
  for (int fc = 0; fc < 4; ++fc) b2v[fc] = bias2[e*DIM + wid*64 + fc*16 + l15];
#pragma unroll
  for (int fr = 0; fr < 4; ++fr) {
#pragma unroll
    for (int j = 0; j < 4; ++j) {
      int r = fr*16 + lr4 + j;
      if (r < rows) {
        int t = etok[r];
        float w = ewgt[r];
#pragma unroll
        for (int fc = 0; fc < 4; ++fc)
          atomicAdd(out + (size_t)t * DIM + wid*64 + fc*16 + l15,
                    w * (accY[fr][fc][j] + b2v[fc]));
      }
    }
  }
}

extern "C" void kernel_launch(void* const* d_in, const int* in_sizes, int n_in,
                              void* d_out, int out_size, void* d_ws, size_t ws_size,
                              hipStream_t stream)
{
  const float* x    = (const float*)d_in[0];
  const float* grad = (const float*)d_in[1];
  const float* Wr   = (const float*)d_in[2];
  const float* br   = (const float*)d_in[3];
  const float* W1   = (const float*)d_in[4];
  const float* b1   = (const float*)d_in[5];
  const float* W2   = (const float*)d_in[6];
  const float* b2   = (const float*)d_in[7];
  float* out   = (float*)d_out;
  float* probs = out + (size_t)N_TOK * DIM;

  char* wsb = (char*)d_ws;
  int*    cnt = (int*)wsb;                                        // 32 B
  int*    tok = (int*)   (wsb + 4096);                            // 1 MB
  float*  wgt = (float*) (wsb + 4096 + (size_t)NEXP*N_TOK*4);     // 1 MB
  ushort* w1t = (ushort*)(wsb + 4096 + (size_t)NEXP*N_TOK*8);     // 4 MB
  ushort* w2t = w1t + (size_t)NEXP * HID * DIM;                   // 4 MB

  hipMemsetAsync(d_out, 0, (size_t)N_TOK * DIM * sizeof(float), stream);
  hipMemsetAsync(cnt, 0, NEXP * sizeof(int), stream);

  k_transpose_cast<<<dim3(HID/32, DIM/32, NEXP), dim3(32, 8), 0, stream>>>(W1, w1t, DIM, HID);
  k_transpose_cast<<<dim3(DIM/32, HID/32, NEXP), dim3(32, 8), 0, stream>>>(W2, w2t, HID, DIM);
  k_router<<<N_TOK/256, 256, 0, stream>>>(x, grad, Wr, br, probs, cnt, tok, wgt);
  k_moe<<<NEXP*MAXT, 256, 0, stream>>>(x, w1t, w2t, b1, b2, cnt, tok, wgt, out);
}

// Round 5
// 596.194 us; speedup vs baseline: 1.0494x; 1.0494x over previous
//
#include <hip/hip_runtime.h>
#include <hip/hip_bf16.h>
#include <cmath>

#define N_TOK 32768
#define DIM   256
#define NEXP  8
#define HID   1024
#define BM    64
#define BH    64
#define MAXT  512   // MAXT*BM == N_TOK: covers worst-case expert load

typedef short bf16x8 __attribute__((ext_vector_type(8)));
typedef float f32x4  __attribute__((ext_vector_type(4)));

__device__ __forceinline__ ushort f2bf(float f) {
  unsigned u = __builtin_bit_cast(unsigned, f);
  u += 0x7fffu + ((u >> 16) & 1u);   // RNE; inputs are well-behaved (no NaN/Inf)
  return (ushort)(u >> 16);
}

// lh swizzle (128B rows): 16B-slot XOR, max 112 < 128 -> bijective in-row.
// Distinct for the C-layout store rows {j, j+4, j+8, j+12}; 2-way on reads.
__device__ __forceinline__ int lh_slot(int row) {
  return ((row ^ (row >> 3)) & 7) << 4;
}
// lx swizzle (512B rows): round-1-proven (r&7)<<4, max 112 < 512, bijective.
// (Round 4's lh_slot(r)<<3 reached 896 > 511 -> cross-row collisions -> wrong A.)
__device__ __forceinline__ int lx_slot(int row) {
  return (row & 7) << 4;
}

// ---------- transpose + cast: src[E][R][C] f32 -> dst[E][C][R] bf16 ----------
__global__ __launch_bounds__(256) void k_transpose_cast(
    const float* __restrict__ src, ushort* __restrict__ dst, int R, int C)
{
  __shared__ float tile[32][33];
  int e = blockIdx.z, rb = blockIdx.y, cb = blockIdx.x;
  int tx = threadIdx.x, ty = threadIdx.y;           // 32 x 8
  const float* s = src + (size_t)e * R * C;
  ushort* d = dst + (size_t)e * R * C;
#pragma unroll
  for (int j = 0; j < 4; ++j)
    tile[ty + 8*j][tx] = s[(size_t)(rb*32 + ty + 8*j) * C + cb*32 + tx];
  __syncthreads();
#pragma unroll
  for (int j = 0; j < 4; ++j)
    d[(size_t)(cb*32 + ty + 8*j) * R + rb*32 + tx] = f2bf(tile[tx][ty + 8*j]);
}

// ---------- router: fp64 logits, softmax, top-2, bucket scatter ----------
__global__ __launch_bounds__(256) void k_router(
    const float* __restrict__ x, const float* __restrict__ grad,
    const float* __restrict__ Wr, const float* __restrict__ br,
    float* __restrict__ probs_out,
    int* __restrict__ cnt, int* __restrict__ tok, float* __restrict__ wgt)
{
  __shared__ float xt[256][33];
  __shared__ float wrs[257*8];
  __shared__ float brs[8];
  __shared__ int lcnt[8], lbase[8];
  int tid = threadIdx.x;
  int n = blockIdx.x * 256 + tid;

  for (int i = tid; i < 257*8; i += 256) wrs[i] = Wr[i];
  if (tid < 8) { brs[tid] = br[tid]; lcnt[tid] = 0; }

  double acc[8] = {0,0,0,0,0,0,0,0};
  for (int ch = 0; ch < 8; ++ch) {
    __syncthreads();
    for (int f = tid; f < 2048; f += 256) {          // 256 rows x 32 cols, float4
      int r = f >> 3, c0 = (f & 7) * 4;
      float4 v = *(const float4*)(x + (size_t)(blockIdx.x*256 + r)*DIM + ch*32 + c0);
      xt[r][c0] = v.x; xt[r][c0+1] = v.y; xt[r][c0+2] = v.z; xt[r][c0+3] = v.w;
    }
    __syncthreads();
#pragma unroll 4
    for (int c = 0; c < 32; ++c) {
      double xv = (double)xt[tid][c];
      const float* wr = &wrs[(ch*32 + c)*8];
#pragma unroll
      for (int e = 0; e < 8; ++e) acc[e] += xv * (double)wr[e];
    }
  }
  double g = (double)grad[n];
  double lg[8];
#pragma unroll
  for (int e = 0; e < 8; ++e) lg[e] = acc[e] + g*(double)wrs[256*8+e] + (double)brs[e];
  double m = lg[0];
#pragma unroll
  for (int e = 1; e < 8; ++e) m = lg[e] > m ? lg[e] : m;
  double p[8], s = 0.0;
#pragma unroll
  for (int e = 0; e < 8; ++e) { p[e] = exp(lg[e]-m); s += p[e]; }
  double inv = 1.0/s;
#pragma unroll
  for (int e = 0; e < 8; ++e) probs_out[(size_t)n*8 + e] = (float)(p[e]*inv);

  // top-2, ties -> lower index (matches lax.top_k)
  int i0 = 0;
#pragma unroll
  for (int e = 1; e < 8; ++e) if (lg[e] > lg[i0]) i0 = e;
  int i1 = (i0 == 0) ? 1 : 0;
#pragma unroll
  for (int e = 0; e < 8; ++e) if (e != i0 && lg[e] > lg[i1]) i1 = e;
  float w0 = (float)(p[i0]*inv), w1 = (float)(p[i1]*inv);

  int p0 = atomicAdd(&lcnt[i0], 1);
  int p1 = atomicAdd(&lcnt[i1], 1);
  __syncthreads();
  if (tid < 8) lbase[tid] = atomicAdd(&cnt[tid], lcnt[tid]);
  __syncthreads();
  tok[i0*N_TOK + lbase[i0] + p0] = n;  wgt[i0*N_TOK + lbase[i0] + p0] = w0;
  tok[i1*N_TOK + lbase[i1] + p1] = n;  wgt[i1*N_TOK + lbase[i1] + p1] = w1;
}

// ---------- fused gathered expert MLP: out += w * (gelu(x@W1+b1)@W2 + b2) ----------
__global__ __launch_bounds__(256, 3) void k_moe(
    const float* __restrict__ x,
    const ushort* __restrict__ w1t,   // [E][H][D] bf16 (transposed)
    const ushort* __restrict__ w2t,   // [E][D][H] bf16 (transposed)
    const float* __restrict__ bias1,  // [E][H]
    const float* __restrict__ bias2,  // [E][D]
    const int* __restrict__ cnt, const int* __restrict__ tok,
    const float* __restrict__ wgt,
    float* __restrict__ out)
{
  // Contiguous per-expert mapping (empirically best for L2: round 1 = 67 MB
  // FETCH). Direct per-wave global A-gather (rounds 2/3) thrashed L2
  // (FETCH 758/938 MB) -> x is staged via LDS with coalesced loads.
  int e    = blockIdx.x / MAXT;
  int tile = blockIdx.x % MAXT;
  int c = cnt[e];
  int row0 = tile * BM;
  if (row0 >= c) return;
  int rows = min(BM, c - row0);

  __shared__ ushort lx[BM * DIM];     // 32 KB, swizzled rows
  __shared__ ushort lh[2][BM * BH];   // 16 KB double-buffered h tile

  int tid  = threadIdx.x;
  int lane = tid & 63;
  int wid  = tid >> 6;
  const int l15 = lane & 15;
  const int lk8 = (lane >> 4) * 8;
  const int lr4 = (lane >> 4) * 4;
  const int wr = wid >> 1, wc = wid & 1;   // 2x2 wave grid for GEMM1

  const int*   etok = tok + e * N_TOK + row0;
  const float* ewgt = wgt + e * N_TOK + row0;

  // ---- stage x rows -> bf16 swizzled LDS (coalesced 1KB-per-instruction) ----
  for (int f = tid; f < BM * (DIM/4); f += 256) {
    int r = f >> 6, c4 = f & 63;
    int t = etok[min(r, rows - 1)];
    float4 v = *(const float4*)(x + (size_t)t * DIM + c4 * 4);
    ushort4 b;
    b.x = f2bf(v.x); b.y = f2bf(v.y); b.z = f2bf(v.z); b.w = f2bf(v.w);
    *(ushort4*)((char*)lx + r * 512 + ((c4 * 8) ^ lx_slot(r))) = b;
  }
  __syncthreads();

  // ---- hoist A-fragments to registers once (lx read 1x, not per chunk) ----
  bf16x8 areg[2][8];
#pragma unroll
  for (int fr = 0; fr < 2; ++fr) {
    int row = wr*32 + fr*16 + l15;
#pragma unroll
    for (int k = 0; k < 8; ++k)
      areg[fr][k] = *(const bf16x8*)((const char*)lx + row*512
                      + (((k*32 + lk8)*2) ^ lx_slot(row)));
  }

  f32x4 accY[4][4];
#pragma unroll
  for (int i = 0; i < 4; ++i)
#pragma unroll
    for (int j = 0; j < 4; ++j) accY[i][j] = (f32x4){0.f,0.f,0.f,0.f};

  const ushort* W1e = w1t + (size_t)e * HID * DIM;
  const ushort* W2e = w2t + (size_t)e * DIM * HID;

  int sl2[4];
#pragma unroll
  for (int fr = 0; fr < 4; ++fr) sl2[fr] = lh_slot(fr*16 + l15);

  for (int chunk = 0; chunk < HID / BH; ++chunk) {
    int h0 = chunk * BH;

    // prefetch this chunk's W2 B-fragments (consumed after the barrier ->
    // latency hides under GEMM1 + GELU)
    bf16x8 bw[2][4];
#pragma unroll
    for (int k2 = 0; k2 < 2; ++k2)
#pragma unroll
      for (int fc = 0; fc < 4; ++fc)
        bw[k2][fc] = *(const bf16x8*)(W2e + (size_t)(wid*64 + fc*16 + l15) * HID
                                      + h0 + k2*32 + lk8);

    f32x4 accH[2][2];
#pragma unroll
    for (int i = 0; i < 2; ++i)
#pragma unroll
      for (int j = 0; j < 2; ++j) accH[i][j] = (f32x4){0.f,0.f,0.f,0.f};

    // GEMM1: h[64x64] = x[64x256] @ W1[256x64], A from registers
#pragma unroll
    for (int k = 0; k < 8; ++k) {
      bf16x8 b0 = *(const bf16x8*)(W1e + (size_t)(h0 + wc*32 +      l15) * DIM + k*32 + lk8);
      bf16x8 b1 = *(const bf16x8*)(W1e + (size_t)(h0 + wc*32 + 16 + l15) * DIM + k*32 + lk8);
      accH[0][0] = __builtin_amdgcn_mfma_f32_16x16x32_bf16(areg[0][k], b0, accH[0][0], 0, 0, 0);
      accH[1][0] = __builtin_amdgcn_mfma_f32_16x16x32_bf16(areg[1][k], b0, accH[1][0], 0, 0, 0);
      accH[0][1] = __builtin_amdgcn_mfma_f32_16x16x32_bf16(areg[0][k], b1, accH[0][1], 0, 0, 0);
      accH[1][1] = __builtin_amdgcn_mfma_f32_16x16x32_bf16(areg[1][k], b1, accH[1][1], 0, 0, 0);
    }

    // exact GELU + bf16 -> swizzled LDS (double buffer, ONE barrier per chunk)
    ushort* lb = lh[chunk & 1];
#pragma unroll
    for (int fc = 0; fc < 2; ++fc) {
      float bv = bias1[e*HID + h0 + wc*32 + fc*16 + l15];
      int col = wc*32 + fc*16 + l15;
#pragma unroll
      for (int fr = 0; fr < 2; ++fr)
#pragma unroll
        for (int j = 0; j < 4; ++j) {
          int row = wr*32 + fr*16 + lr4 + j;
          float v = accH[fr][fc][j] + bv;
          v = 0.5f * v * (1.0f + erff(v * 0.70710678118654752f));
          *(ushort*)((char*)lb + row*128 + ((col*2) ^ lh_slot(row))) = f2bf(v);
        }
    }
    __syncthreads();

    // GEMM2: y[64x256] += h[64x64] @ W2[64x256], B from prefetched regs
#pragma unroll
    for (int k2 = 0; k2 < 2; ++k2) {
      bf16x8 a2[4];
#pragma unroll
      for (int fr = 0; fr < 4; ++fr) {
        int row = fr*16 + l15;
        a2[fr] = *(const bf16x8*)((const char*)lb + row*128 + (((k2*32 + lk8)*2) ^ sl2[fr]));
      }
#pragma unroll
      for (int fr = 0; fr < 4; ++fr)
#pragma unroll
        for (int fc = 0; fc < 4; ++fc)
          accY[fr][fc] = __builtin_amdgcn_mfma_f32_16x16x32_bf16(a2[fr], bw[k2][fc], accY[fr][fc], 0, 0, 0);
    }
  }

  // epilogue: out[t] += w * (y + b2)
  float b2v[4];
#pragma unroll
  for (int fc = 0; fc < 4; ++fc) b2v[fc] = bias2[e*DIM + wid*64 + fc*16 + l15];
#pragma unroll
  for (int fr = 0; fr < 4; ++fr) {
#pragma unroll
    for (int j = 0; j < 4; ++j) {
      int r = fr*16 + lr4 + j;
      if (r < rows) {
        int t = etok[r];
        float w = ewgt[r];
#pragma unroll
        for (int fc = 0; fc < 4; ++fc)
          atomicAdd(out + (size_t)t * DIM + wid*64 + fc*16 + l15,
                    w * (accY[fr][fc][j] + b2v[fc]));
      }
    }
  }
}

extern "C" void kernel_launch(void* const* d_in, const int* in_sizes, int n_in,
                              void* d_out, int out_size, void* d_ws, size_t ws_size,
                              hipStream_t stream)
{
  const float* x    = (const float*)d_in[0];
  const float* grad = (const float*)d_in[1];
  const float* Wr   = (const float*)d_in[2];
  const float* br   = (const float*)d_in[3];
  const float* W1   = (const float*)d_in[4];
  const float* b1   = (const float*)d_in[5];
  const float* W2   = (const float*)d_in[6];
  const float* b2   = (const float*)d_in[7];
  float* out   = (float*)d_out;
  float* probs = out + (size_t)N_TOK * DIM;

  char* wsb = (char*)d_ws;
  int*    cnt = (int*)wsb;                                        // 32 B
  int*    tok = (int*)   (wsb + 4096);                            // 1 MB
  float*  wgt = (float*) (wsb + 4096 + (size_t)NEXP*N_TOK*4);     // 1 MB
  ushort* w1t = (ushort*)(wsb + 4096 + (size_t)NEXP*N_TOK*8);     // 4 MB
  ushort* w2t = w1t + (size_t)NEXP * HID * DIM;                   // 4 MB

  hipMemsetAsync(d_out, 0, (size_t)N_TOK * DIM * sizeof(float), stream);
  hipMemsetAsync(cnt, 0, NEXP * sizeof(int), stream);

  k_transpose_cast<<<dim3(HID/32, DIM/32, NEXP), dim3(32, 8), 0, stream>>>(W1, w1t, DIM, HID);
  k_transpose_cast<<<dim3(DIM/32, HID/32, NEXP), dim3(32, 8), 0, stream>>>(W2, w2t, HID, DIM);
  k_router<<<N_TOK/256, 256, 0, stream>>>(x, grad, Wr, br, probs, cnt, tok, wgt);
  k_moe<<<NEXP*MAXT, 256, 0, stream>>>(x, w1t, w2t, b1, b2, cnt, tok, wgt, out);
}

// Round 6
// 383.093 us; speedup vs baseline: 1.6332x; 1.5563x over previous
//
#include <hip/hip_runtime.h>
#include <hip/hip_bf16.h>
#include <cmath>

#define N_TOK 32768
#define DIM   256
#define NEXP  8
#define HID   1024
#define BM    64
#define BH    64
#define MAXT  512   // MAXT*BM == N_TOK: covers worst-case expert load

typedef short bf16x8 __attribute__((ext_vector_type(8)));
typedef float f32x4  __attribute__((ext_vector_type(4)));

__device__ __forceinline__ ushort f2bf(float f) {
  unsigned u = __builtin_bit_cast(unsigned, f);
  u += 0x7fffu + ((u >> 16) & 1u);   // RNE; inputs are well-behaved (no NaN/Inf)
  return (ushort)(u >> 16);
}

// lh swizzle (128B rows): 16B-slot XOR, max 112 < 128 -> bijective in-row.
// Distinct for the C-layout store rows {j, j+4, j+8, j+12}; 2-way on reads.
__device__ __forceinline__ int lh_slot(int row) {
  return ((row ^ (row >> 3)) & 7) << 4;
}
// lx swizzle (512B rows): round-1-proven (r&7)<<4, max 112 < 512, bijective.
__device__ __forceinline__ int lx_slot(int row) {
  return (row & 7) << 4;
}

// ---------- transpose + cast: src[E][R][C] f32 -> dst[E][C][R] bf16 ----------
__global__ __launch_bounds__(256) void k_transpose_cast(
    const float* __restrict__ src, ushort* __restrict__ dst, int R, int C)
{
  __shared__ float tile[32][33];
  int e = blockIdx.z, rb = blockIdx.y, cb = blockIdx.x;
  int tx = threadIdx.x, ty = threadIdx.y;           // 32 x 8
  const float* s = src + (size_t)e * R * C;
  ushort* d = dst + (size_t)e * R * C;
#pragma unroll
  for (int j = 0; j < 4; ++j)
    tile[ty + 8*j][tx] = s[(size_t)(rb*32 + ty + 8*j) * C + cb*32 + tx];
  __syncthreads();
#pragma unroll
  for (int j = 0; j < 4; ++j)
    d[(size_t)(cb*32 + ty + 8*j) * R + rb*32 + tx] = f2bf(tile[tx][ty + 8*j]);
}

// ---------- router: fp64 logits, softmax, top-2, bucket scatter ----------
__global__ __launch_bounds__(256) void k_router(
    const float* __restrict__ x, const float* __restrict__ grad,
    const float* __restrict__ Wr, const float* __restrict__ br,
    float* __restrict__ probs_out,
    int* __restrict__ cnt, int* __restrict__ tok, float* __restrict__ wgt)
{
  __shared__ float xt[256][33];
  __shared__ float wrs[257*8];
  __shared__ float brs[8];
  __shared__ int lcnt[8], lbase[8];
  int tid = threadIdx.x;
  int n = blockIdx.x * 256 + tid;

  for (int i = tid; i < 257*8; i += 256) wrs[i] = Wr[i];
  if (tid < 8) { brs[tid] = br[tid]; lcnt[tid] = 0; }

  double acc[8] = {0,0,0,0,0,0,0,0};
  for (int ch = 0; ch < 8; ++ch) {
    __syncthreads();
    for (int f = tid; f < 2048; f += 256) {          // 256 rows x 32 cols, float4
      int r = f >> 3, c0 = (f & 7) * 4;
      float4 v = *(const float4*)(x + (size_t)(blockIdx.x*256 + r)*DIM + ch*32 + c0);
      xt[r][c0] = v.x; xt[r][c0+1] = v.y; xt[r][c0+2] = v.z; xt[r][c0+3] = v.w;
    }
    __syncthreads();
#pragma unroll 4
    for (int c = 0; c < 32; ++c) {
      double xv = (double)xt[tid][c];
      const float* wr = &wrs[(ch*32 + c)*8];
#pragma unroll
      for (int e = 0; e < 8; ++e) acc[e] += xv * (double)wr[e];
    }
  }
  double g = (double)grad[n];
  double lg[8];
#pragma unroll
  for (int e = 0; e < 8; ++e) lg[e] = acc[e] + g*(double)wrs[256*8+e] + (double)brs[e];
  double m = lg[0];
#pragma unroll
  for (int e = 1; e < 8; ++e) m = lg[e] > m ? lg[e] : m;
  double p[8], s = 0.0;
#pragma unroll
  for (int e = 0; e < 8; ++e) { p[e] = exp(lg[e]-m); s += p[e]; }
  double inv = 1.0/s;
#pragma unroll
  for (int e = 0; e < 8; ++e) probs_out[(size_t)n*8 + e] = (float)(p[e]*inv);

  // top-2, ties -> lower index (matches lax.top_k)
  int i0 = 0;
#pragma unroll
  for (int e = 1; e < 8; ++e) if (lg[e] > lg[i0]) i0 = e;
  int i1 = (i0 == 0) ? 1 : 0;
#pragma unroll
  for (int e = 0; e < 8; ++e) if (e != i0 && lg[e] > lg[i1]) i1 = e;
  float w0 = (float)(p[i0]*inv), w1 = (float)(p[i1]*inv);

  int p0 = atomicAdd(&lcnt[i0], 1);
  int p1 = atomicAdd(&lcnt[i1], 1);
  __syncthreads();
  if (tid < 8) lbase[tid] = atomicAdd(&cnt[tid], lcnt[tid]);
  __syncthreads();
  tok[i0*N_TOK + lbase[i0] + p0] = n;  wgt[i0*N_TOK + lbase[i0] + p0] = w0;
  tok[i1*N_TOK + lbase[i1] + p1] = n;  wgt[i1*N_TOK + lbase[i1] + p1] = w1;
}

// ---------- fused gathered expert MLP: out += w * (gelu(x@W1+b1)@W2 + b2) ----------
// launch_bounds (256,2): VGPR cap 256/wave. Register demand is ~210 unified
// (areg 64 + accY 64 + bw 32 + accH 16 + addr). Rounds 2/3/5 used (256,4)/(256,3)
// -> caps 128/168 -> SPILL TO SCRATCH = the FETCH 530-938 MB + WRITE 141-302 MB
// explosions. Do NOT tighten this bound without re-checking scratch usage.
__global__ __launch_bounds__(256, 2) void k_moe(
    const float* __restrict__ x,
    const ushort* __restrict__ w1t,   // [E][H][D] bf16 (transposed)
    const ushort* __restrict__ w2t,   // [E][D][H] bf16 (transposed)
    const float* __restrict__ bias1,  // [E][H]
    const float* __restrict__ bias2,  // [E][D]
    const int* __restrict__ cnt, const int* __restrict__ tok,
    const float* __restrict__ wgt,
    float* __restrict__ out)
{
  int e    = blockIdx.x / MAXT;
  int tile = blockIdx.x % MAXT;
  int c = cnt[e];
  int row0 = tile * BM;
  if (row0 >= c) return;
  int rows = min(BM, c - row0);

  __shared__ ushort lx[BM * DIM];     // 32 KB, swizzled rows
  __shared__ ushort lh[2][BM * BH];   // 16 KB double-buffered h tile

  int tid  = threadIdx.x;
  int lane = tid & 63;
  int wid  = tid >> 6;
  const int l15 = lane & 15;
  const int lk8 = (lane >> 4) * 8;
  const int lr4 = (lane >> 4) * 4;
  const int wr = wid >> 1, wc = wid & 1;   // 2x2 wave grid for GEMM1

  const int*   etok = tok + e * N_TOK + row0;
  const float* ewgt = wgt + e * N_TOK + row0;

  // ---- stage x rows -> bf16 swizzled LDS (coalesced 1KB-per-instruction) ----
  for (int f = tid; f < BM * (DIM/4); f += 256) {
    int r = f >> 6, c4 = f & 63;
    int t = etok[min(r, rows - 1)];
    float4 v = *(const float4*)(x + (size_t)t * DIM + c4 * 4);
    ushort4 b;
    b.x = f2bf(v.x); b.y = f2bf(v.y); b.z = f2bf(v.z); b.w = f2bf(v.w);
    *(ushort4*)((char*)lx + r * 512 + ((c4 * 8) ^ lx_slot(r))) = b;
  }
  __syncthreads();

  // ---- hoist A-fragments to registers once (lx read 1x, not per chunk) ----
  bf16x8 areg[2][8];
#pragma unroll
  for (int fr = 0; fr < 2; ++fr) {
    int row = wr*32 + fr*16 + l15;
#pragma unroll
    for (int k = 0; k < 8; ++k)
      areg[fr][k] = *(const bf16x8*)((const char*)lx + row*512
                      + (((k*32 + lk8)*2) ^ lx_slot(row)));
  }

  f32x4 accY[4][4];
#pragma unroll
  for (int i = 0; i < 4; ++i)
#pragma unroll
    for (int j = 0; j < 4; ++j) accY[i][j] = (f32x4){0.f,0.f,0.f,0.f};

  const ushort* W1e = w1t + (size_t)e * HID * DIM;
  const ushort* W2e = w2t + (size_t)e * DIM * HID;

  int sl2[4];
#pragma unroll
  for (int fr = 0; fr < 4; ++fr) sl2[fr] = lh_slot(fr*16 + l15);

  for (int chunk = 0; chunk < HID / BH; ++chunk) {
    int h0 = chunk * BH;

    // prefetch this chunk's W2 B-fragments (consumed after the barrier ->
    // latency hides under GEMM1 + GELU)
    bf16x8 bw[2][4];
#pragma unroll
    for (int k2 = 0; k2 < 2; ++k2)
#pragma unroll
      for (int fc = 0; fc < 4; ++fc)
        bw[k2][fc] = *(const bf16x8*)(W2e + (size_t)(wid*64 + fc*16 + l15) * HID
                                      + h0 + k2*32 + lk8);

    f32x4 accH[2][2];
#pragma unroll
    for (int i = 0; i < 2; ++i)
#pragma unroll
      for (int j = 0; j < 2; ++j) accH[i][j] = (f32x4){0.f,0.f,0.f,0.f};

    // GEMM1: h[64x64] = x[64x256] @ W1[256x64], A from registers
#pragma unroll
    for (int k = 0; k < 8; ++k) {
      bf16x8 b0 = *(const bf16x8*)(W1e + (size_t)(h0 + wc*32 +      l15) * DIM + k*32 + lk8);
      bf16x8 b1 = *(const bf16x8*)(W1e + (size_t)(h0 + wc*32 + 16 + l15) * DIM + k*32 + lk8);
      accH[0][0] = __builtin_amdgcn_mfma_f32_16x16x32_bf16(areg[0][k], b0, accH[0][0], 0, 0, 0);
      accH[1][0] = __builtin_amdgcn_mfma_f32_16x16x32_bf16(areg[1][k], b0, accH[1][0], 0, 0, 0);
      accH[0][1] = __builtin_amdgcn_mfma_f32_16x16x32_bf16(areg[0][k], b1, accH[0][1], 0, 0, 0);
      accH[1][1] = __builtin_amdgcn_mfma_f32_16x16x32_bf16(areg[1][k], b1, accH[1][1], 0, 0, 0);
    }

    // exact GELU + bf16 -> swizzled LDS (double buffer, ONE barrier per chunk)
    ushort* lb = lh[chunk & 1];
#pragma unroll
    for (int fc = 0; fc < 2; ++fc) {
      float bv = bias1[e*HID + h0 + wc*32 + fc*16 + l15];
      int col = wc*32 + fc*16 + l15;
#pragma unroll
      for (int fr = 0; fr < 2; ++fr)
#pragma unroll
        for (int j = 0; j < 4; ++j) {
          int row = wr*32 + fr*16 + lr4 + j;
          float v = accH[fr][fc][j] + bv;
          v = 0.5f * v * (1.0f + erff(v * 0.70710678118654752f));
          *(ushort*)((char*)lb + row*128 + ((col*2) ^ lh_slot(row))) = f2bf(v);
        }
    }
    __syncthreads();

    // GEMM2: y[64x256] += h[64x64] @ W2[64x256], B from prefetched regs
#pragma unroll
    for (int k2 = 0; k2 < 2; ++k2) {
      bf16x8 a2[4];
#pragma unroll
      for (int fr = 0; fr < 4; ++fr) {
        int row = fr*16 + l15;
        a2[fr] = *(const bf16x8*)((const char*)lb + row*128 + (((k2*32 + lk8)*2) ^ sl2[fr]));
      }
#pragma unroll
      for (int fr = 0; fr < 4; ++fr)
#pragma unroll
        for (int fc = 0; fc < 4; ++fc)
          accY[fr][fc] = __builtin_amdgcn_mfma_f32_16x16x32_bf16(a2[fr], bw[k2][fc], accY[fr][fc], 0, 0, 0);
    }
  }

  // epilogue: out[t] += w * (y + b2)
  float b2v[4];
#pragma unroll
  for (int fc = 0; fc < 4; ++fc) b2v[fc] = bias2[e*DIM + wid*64 + fc*16 + l15];
#pragma unroll
  for (int fr = 0; fr < 4; ++fr) {
#pragma unroll
    for (int j = 0; j < 4; ++j) {
      int r = fr*16 + lr4 + j;
      if (r < rows) {
        int t = etok[r];
        float w = ewgt[r];
#pragma unroll
        for (int fc = 0; fc < 4; ++fc)
          atomicAdd(out + (size_t)t * DIM + wid*64 + fc*16 + l15,
                    w * (accY[fr][fc][j] + b2v[fc]));
      }
    }
  }
}

extern "C" void kernel_launch(void* const* d_in, const int* in_sizes, int n_in,
                              void* d_out, int out_size, void* d_ws, size_t ws_size,
                              hipStream_t stream)
{
  const float* x    = (const float*)d_in[0];
  const float* grad = (const float*)d_in[1];
  const float* Wr   = (const float*)d_in[2];
  const float* br   = (const float*)d_in[3];
  const float* W1   = (const float*)d_in[4];
  const float* b1   = (const float*)d_in[5];
  const float* W2   = (const float*)d_in[6];
  const float* b2   = (const float*)d_in[7];
  float* out   = (float*)d_out;
  float* probs = out + (size_t)N_TOK * DIM;

  char* wsb = (char*)d_ws;
  int*    cnt = (int*)wsb;                                        // 32 B
  int*    tok = (int*)   (wsb + 4096);                            // 1 MB
  float*  wgt = (float*) (wsb + 4096 + (size_t)NEXP*N_TOK*4);     // 1 MB
  ushort* w1t = (ushort*)(wsb + 4096 + (size_t)NEXP*N_TOK*8);     // 4 MB
  ushort* w2t = w1t + (size_t)NEXP * HID * DIM;                   // 4 MB

  hipMemsetAsync(d_out, 0, (size_t)N_TOK * DIM * sizeof(float), stream);
  hipMemsetAsync(cnt, 0, NEXP * sizeof(int), stream);

  k_transpose_cast<<<dim3(HID/32, DIM/32, NEXP), dim3(32, 8), 0, stream>>>(W1, w1t, DIM, HID);
  k_transpose_cast<<<dim3(DIM/32, HID/32, NEXP), dim3(32, 8), 0, stream>>>(W2, w2t, HID, DIM);
  k_router<<<N_TOK/256, 256, 0, stream>>>(x, grad, Wr, br, probs, cnt, tok, wgt);
  k_moe<<<NEXP*MAXT, 256, 0, stream>>>(x, w1t, w2t, b1, b2, cnt, tok, wgt, out);
}

// Round 7
// 371.278 us; speedup vs baseline: 1.6851x; 1.0318x over previous
//
#include <hip/hip_runtime.h>
#include <hip/hip_bf16.h>
#include <cmath>

#define N_TOK 32768
#define DIM   256
#define NEXP  8
#define HID   1024
#define BM    64
#define BH    64
#define MAXT  512   // MAXT*BM == N_TOK: covers worst-case expert load

typedef short bf16x8 __attribute__((ext_vector_type(8)));
typedef float f32x4  __attribute__((ext_vector_type(4)));

__device__ __forceinline__ ushort f2bf(float f) {
  unsigned u = __builtin_bit_cast(unsigned, f);
  u += 0x7fffu + ((u >> 16) & 1u);   // RNE; inputs are well-behaved (no NaN/Inf)
  return (ushort)(u >> 16);
}

// lh swizzle (128B rows): 16B-slot XOR, max 112 < 128 -> bijective in-row.
// Distinct for the C-layout store rows {j, j+4, j+8, j+12}; 2-way on reads.
__device__ __forceinline__ int lh_slot(int row) {
  return ((row ^ (row >> 3)) & 7) << 4;
}
// lx swizzle (512B rows): round-1-proven (r&7)<<4, max 112 < 512, bijective.
__device__ __forceinline__ int lx_slot(int row) {
  return (row & 7) << 4;
}

// ---------- transpose + cast: src[E][R][C] f32 -> dst[E][C][R] bf16 ----------
__global__ __launch_bounds__(256) void k_transpose_cast(
    const float* __restrict__ src, ushort* __restrict__ dst, int R, int C)
{
  __shared__ float tile[32][33];
  int e = blockIdx.z, rb = blockIdx.y, cb = blockIdx.x;
  int tx = threadIdx.x, ty = threadIdx.y;           // 32 x 8
  const float* s = src + (size_t)e * R * C;
  ushort* d = dst + (size_t)e * R * C;
#pragma unroll
  for (int j = 0; j < 4; ++j)
    tile[ty + 8*j][tx] = s[(size_t)(rb*32 + ty + 8*j) * C + cb*32 + tx];
  __syncthreads();
#pragma unroll
  for (int j = 0; j < 4; ++j)
    d[(size_t)(cb*32 + ty + 8*j) * R + rb*32 + tx] = f2bf(tile[tx][ty + 8*j]);
}

// ---------- router: fp64 logits, softmax, top-2, bucket scatter ----------
__global__ __launch_bounds__(256) void k_router(
    const float* __restrict__ x, const float* __restrict__ grad,
    const float* __restrict__ Wr, const float* __restrict__ br,
    float* __restrict__ probs_out,
    int* __restrict__ cnt, int* __restrict__ tok, float* __restrict__ wgt)
{
  __shared__ float xt[256][33];
  __shared__ float wrs[257*8];
  __shared__ float brs[8];
  __shared__ int lcnt[8], lbase[8];
  int tid = threadIdx.x;
  int n = blockIdx.x * 256 + tid;

  for (int i = tid; i < 257*8; i += 256) wrs[i] = Wr[i];
  if (tid < 8) { brs[tid] = br[tid]; lcnt[tid] = 0; }

  double acc[8] = {0,0,0,0,0,0,0,0};
  for (int ch = 0; ch < 8; ++ch) {
    __syncthreads();
    for (int f = tid; f < 2048; f += 256) {          // 256 rows x 32 cols, float4
      int r = f >> 3, c0 = (f & 7) * 4;
      float4 v = *(const float4*)(x + (size_t)(blockIdx.x*256 + r)*DIM + ch*32 + c0);
      xt[r][c0] = v.x; xt[r][c0+1] = v.y; xt[r][c0+2] = v.z; xt[r][c0+3] = v.w;
    }
    __syncthreads();
#pragma unroll 4
    for (int c = 0; c < 32; ++c) {
      double xv = (double)xt[tid][c];
      const float* wr = &wrs[(ch*32 + c)*8];
#pragma unroll
      for (int e = 0; e < 8; ++e) acc[e] += xv * (double)wr[e];
    }
  }
  double g = (double)grad[n];
  double lg[8];
#pragma unroll
  for (int e = 0; e < 8; ++e) lg[e] = acc[e] + g*(double)wrs[256*8+e] + (double)brs[e];
  double m = lg[0];
#pragma unroll
  for (int e = 1; e < 8; ++e) m = lg[e] > m ? lg[e] : m;
  double p[8], s = 0.0;
#pragma unroll
  for (int e = 0; e < 8; ++e) { p[e] = exp(lg[e]-m); s += p[e]; }
  double inv = 1.0/s;
#pragma unroll
  for (int e = 0; e < 8; ++e) probs_out[(size_t)n*8 + e] = (float)(p[e]*inv);

  // top-2, ties -> lower index (matches lax.top_k)
  int i0 = 0;
#pragma unroll
  for (int e = 1; e < 8; ++e) if (lg[e] > lg[i0]) i0 = e;
  int i1 = (i0 == 0) ? 1 : 0;
#pragma unroll
  for (int e = 0; e < 8; ++e) if (e != i0 && lg[e] > lg[i1]) i1 = e;
  float w0 = (float)(p[i0]*inv), w1 = (float)(p[i1]*inv);

  int p0 = atomicAdd(&lcnt[i0], 1);
  int p1 = atomicAdd(&lcnt[i1], 1);
  __syncthreads();
  if (tid < 8) lbase[tid] = atomicAdd(&cnt[tid], lcnt[tid]);
  __syncthreads();
  tok[i0*N_TOK + lbase[i0] + p0] = n;  wgt[i0*N_TOK + lbase[i0] + p0] = w0;
  tok[i1*N_TOK + lbase[i1] + p1] = n;  wgt[i1*N_TOK + lbase[i1] + p1] = w1;
}

// ---------- fused gathered expert MLP: out += w * (gelu(x@W1+b1)@W2 + b2) ----------
// launch_bounds (256,2): VGPR cap 256/wave. Register demand is ~210 unified.
// (256,4)/(256,3) caps (128/168) caused SPILL TO SCRATCH = FETCH 530-938 MB.
// Do NOT tighten this bound without re-checking scratch usage.
//
// Block->expert mapping e = bid & 7: with the bid%8 -> XCD round-robin
// dispatch, XCD x runs ONLY expert x, so its 1 MB of bf16 weights stays
// L2-resident (4 MB/XCD). The contiguous mapping (e = bid/MAXT) makes every
// XCD touch all 8 experts concurrently (8 MB > 4 MB L2) -> weight loads fall
// to L3 latency. (Round 2 tested this mapping but was confounded by spills.)
__global__ __launch_bounds__(256, 2) void k_moe(
    const float* __restrict__ x,
    const ushort* __restrict__ w1t,   // [E][H][D] bf16 (transposed)
    const ushort* __restrict__ w2t,   // [E][D][H] bf16 (transposed)
    const float* __restrict__ bias1,  // [E][H]
    const float* __restrict__ bias2,  // [E][D]
    const int* __restrict__ cnt, const int* __restrict__ tok,
    const float* __restrict__ wgt,
    float* __restrict__ out)
{
  int e    = blockIdx.x & 7;
  int tile = blockIdx.x >> 3;
  int c = cnt[e];
  int row0 = tile * BM;
  if (row0 >= c) return;
  int rows = min(BM, c - row0);

  __shared__ ushort lx[BM * DIM];     // 32 KB, swizzled rows
  __shared__ ushort lh[2][BM * BH];   // 16 KB double-buffered h tile

  int tid  = threadIdx.x;
  int lane = tid & 63;
  int wid  = tid >> 6;
  const int l15 = lane & 15;
  const int lk8 = (lane >> 4) * 8;
  const int lr4 = (lane >> 4) * 4;
  const int wr = wid >> 1, wc = wid & 1;   // 2x2 wave grid for GEMM1

  const int*   etok = tok + e * N_TOK + row0;
  const float* ewgt = wgt + e * N_TOK + row0;

  // ---- stage x rows -> bf16 swizzled LDS (coalesced 1KB-per-instruction) ----
  for (int f = tid; f < BM * (DIM/4); f += 256) {
    int r = f >> 6, c4 = f & 63;
    int t = etok[min(r, rows - 1)];
    float4 v = *(const float4*)(x + (size_t)t * DIM + c4 * 4);
    ushort4 b;
    b.x = f2bf(v.x); b.y = f2bf(v.y); b.z = f2bf(v.z); b.w = f2bf(v.w);
    *(ushort4*)((char*)lx + r * 512 + ((c4 * 8) ^ lx_slot(r))) = b;
  }
  __syncthreads();

  // ---- hoist A-fragments to registers once (lx read 1x, not per chunk) ----
  bf16x8 areg[2][8];
#pragma unroll
  for (int fr = 0; fr < 2; ++fr) {
    int row = wr*32 + fr*16 + l15;
#pragma unroll
    for (int k = 0; k < 8; ++k)
      areg[fr][k] = *(const bf16x8*)((const char*)lx + row*512
                      + (((k*32 + lk8)*2) ^ lx_slot(row)));
  }

  f32x4 accY[4][4];
#pragma unroll
  for (int i = 0; i < 4; ++i)
#pragma unroll
    for (int j = 0; j < 4; ++j) accY[i][j] = (f32x4){0.f,0.f,0.f,0.f};

  const ushort* W1e = w1t + (size_t)e * HID * DIM;
  const ushort* W2e = w2t + (size_t)e * DIM * HID;

  int sl2[4];
#pragma unroll
  for (int fr = 0; fr < 4; ++fr) sl2[fr] = lh_slot(fr*16 + l15);

  for (int chunk = 0; chunk < HID / BH; ++chunk) {
    int h0 = chunk * BH;

    // prefetch this chunk's W2 B-fragments (consumed after the barrier ->
    // latency hides under GEMM1 + GELU)
    bf16x8 bw[2][4];
#pragma unroll
    for (int k2 = 0; k2 < 2; ++k2)
#pragma unroll
      for (int fc = 0; fc < 4; ++fc)
        bw[k2][fc] = *(const bf16x8*)(W2e + (size_t)(wid*64 + fc*16 + l15) * HID
                                      + h0 + k2*32 + lk8);

    f32x4 accH[2][2];
#pragma unroll
    for (int i = 0; i < 2; ++i)
#pragma unroll
      for (int j = 0; j < 2; ++j) accH[i][j] = (f32x4){0.f,0.f,0.f,0.f};

    // GEMM1: h[64x64] = x[64x256] @ W1[256x64], A from registers
#pragma unroll
    for (int k = 0; k < 8; ++k) {
      bf16x8 b0 = *(const bf16x8*)(W1e + (size_t)(h0 + wc*32 +      l15) * DIM + k*32 + lk8);
      bf16x8 b1 = *(const bf16x8*)(W1e + (size_t)(h0 + wc*32 + 16 + l15) * DIM + k*32 + lk8);
      accH[0][0] = __builtin_amdgcn_mfma_f32_16x16x32_bf16(areg[0][k], b0, accH[0][0], 0, 0, 0);
      accH[1][0] = __builtin_amdgcn_mfma_f32_16x16x32_bf16(areg[1][k], b0, accH[1][0], 0, 0, 0);
      accH[0][1] = __builtin_amdgcn_mfma_f32_16x16x32_bf16(areg[0][k], b1, accH[0][1], 0, 0, 0);
      accH[1][1] = __builtin_amdgcn_mfma_f32_16x16x32_bf16(areg[1][k], b1, accH[1][1], 0, 0, 0);
    }

    // exact GELU + bf16 -> swizzled LDS (double buffer, ONE barrier per chunk)
    ushort* lb = lh[chunk & 1];
#pragma unroll
    for (int fc = 0; fc < 2; ++fc) {
      float bv = bias1[e*HID + h0 + wc*32 + fc*16 + l15];
      int col = wc*32 + fc*16 + l15;
#pragma unroll
      for (int fr = 0; fr < 2; ++fr)
#pragma unroll
        for (int j = 0; j < 4; ++j) {
          int row = wr*32 + fr*16 + lr4 + j;
          float v = accH[fr][fc][j] + bv;
          v = 0.5f * v * (1.0f + erff(v * 0.70710678118654752f));
          *(ushort*)((char*)lb + row*128 + ((col*2) ^ lh_slot(row))) = f2bf(v);
        }
    }
    __syncthreads();

    // GEMM2: y[64x256] += h[64x64] @ W2[64x256], B from prefetched regs
#pragma unroll
    for (int k2 = 0; k2 < 2; ++k2) {
      bf16x8 a2[4];
#pragma unroll
      for (int fr = 0; fr < 4; ++fr) {
        int row = fr*16 + l15;
        a2[fr] = *(const bf16x8*)((const char*)lb + row*128 + (((k2*32 + lk8)*2) ^ sl2[fr]));
      }
#pragma unroll
      for (int fr = 0; fr < 4; ++fr)
#pragma unroll
        for (int fc = 0; fc < 4; ++fc)
          accY[fr][fc] = __builtin_amdgcn_mfma_f32_16x16x32_bf16(a2[fr], bw[k2][fc], accY[fr][fc], 0, 0, 0);
    }
  }

  // epilogue: out[t] += w * (y + b2)
  float b2v[4];
#pragma unroll
  for (int fc = 0; fc < 4; ++fc) b2v[fc] = bias2[e*DIM + wid*64 + fc*16 + l15];
#pragma unroll
  for (int fr = 0; fr < 4; ++fr) {
#pragma unroll
    for (int j = 0; j < 4; ++j) {
      int r = fr*16 + lr4 + j;
      if (r < rows) {
        int t = etok[r];
        float w = ewgt[r];
#pragma unroll
        for (int fc = 0; fc < 4; ++fc)
          atomicAdd(out + (size_t)t * DIM + wid*64 + fc*16 + l15,
                    w * (accY[fr][fc][j] + b2v[fc]));
      }
    }
  }
}

extern "C" void kernel_launch(void* const* d_in, const int* in_sizes, int n_in,
                              void* d_out, int out_size, void* d_ws, size_t ws_size,
                              hipStream_t stream)
{
  const float* x    = (const float*)d_in[0];
  const float* grad = (const float*)d_in[1];
  const float* Wr   = (const float*)d_in[2];
  const float* br   = (const float*)d_in[3];
  const float* W1   = (const float*)d_in[4];
  const float* b1   = (const float*)d_in[5];
  const float* W2   = (const float*)d_in[6];
  const float* b2   = (const float*)d_in[7];
  float* out   = (float*)d_out;
  float* probs = out + (size_t)N_TOK * DIM;

  char* wsb = (char*)d_ws;
  int*    cnt = (int*)wsb;                                        // 32 B
  int*    tok = (int*)   (wsb + 4096);                            // 1 MB
  float*  wgt = (float*) (wsb + 4096 + (size_t)NEXP*N_TOK*4);     // 1 MB
  ushort* w1t = (ushort*)(wsb + 4096 + (size_t)NEXP*N_TOK*8);     // 4 MB
  ushort* w2t = w1t + (size_t)NEXP * HID * DIM;                   // 4 MB

  hipMemsetAsync(d_out, 0, (size_t)N_TOK * DIM * sizeof(float), stream);
  hipMemsetAsync(cnt, 0, NEXP * sizeof(int), stream);

  k_transpose_cast<<<dim3(HID/32, DIM/32, NEXP), dim3(32, 8), 0, stream>>>(W1, w1t, DIM, HID);
  k_transpose_cast<<<dim3(DIM/32, HID/32, NEXP), dim3(32, 8), 0, stream>>>(W2, w2t, HID, DIM);
  k_router<<<N_TOK/256, 256, 0, stream>>>(x, grad, Wr, br, probs, cnt, tok, wgt);
  k_moe<<<NEXP*MAXT, 256, 0, stream>>>(x, w1t, w2t, b1, b2, cnt, tok, wgt, out);
}